// Round 3
// baseline (194.875 us; speedup 1.0000x reference)
//
#include <hip/hip_runtime.h>
#include <math.h>

// RMAC for x[64][512][32][32] fp32, L=3, OVR=0.4, EPS=1e-6.
// Region set (verified exact, absmax 0.0 in rounds 1-2):
//   r0 (0,0,32) weight 2; r1-4 l=2 wl=21 off {0,11}^2; r5-13 l=3 wl=16 off {0,8,16}^2
// Round-3 structure: coalesced float4 loads -> LDS transpose (stride 36,
// b128 writes, conflict-free column reads) -> per-column row-range maxes
// (compile-time predicates) -> 14 region column-range reductions.

#define B_ 64
#define C_ 512
#define BC 32768            // B_*C_
#define TPB 4               // tiles (b,c pairs) per block
#define LSTR 36             // LDS row stride: 36*4B -> b128-aligned writes, conflict-free col reads

__global__ __launch_bounds__(256) void rmac_pool_kernel(const float* __restrict__ x,
                                                        float* __restrict__ vt) {
    __shared__ __align__(16) float lds[TPB][32 * LSTR];   // 18.4 KB
    __shared__ float rmax[TPB][6][32];                    //  3.0 KB

    const int t = threadIdx.x;
    const float4* xv = (const float4*)(x + (long long)blockIdx.x * (TPB * 1024));

    // ---- coalesced load: 4 x (256 consecutive float4) = 4 KB per instruction ----
    float4 v[TPB];
#pragma unroll
    for (int i = 0; i < TPB; ++i) v[i] = xv[i * 256 + t];   // tile i, element t

    const int h  = t >> 3;      // row within tile
    const int w4 = t & 7;       // float4 group within row
#pragma unroll
    for (int i = 0; i < TPB; ++i)
        *(float4*)(&lds[i][h * LSTR + 4 * w4]) = v[i];      // ds_write_b128
    __syncthreads();

    // ---- per-column row-range maxes: thread = (tile, col), 128 active ----
    if (t < TPB * 32) {
        const int tile = t >> 5;
        const int w    = t & 31;
        const float* col = &lds[tile][w];
        float m0 = -INFINITY, m1 = -INFINITY, m2 = -INFINITY;
        float m3 = -INFINITY, m4 = -INFINITY, m5 = -INFINITY;
#pragma unroll
        for (int hh = 0; hh < 32; ++hh) {       // compile-time predicates after unroll
            float e = col[hh * LSTR];
            m0 = fmaxf(m0, e);                         // rows [0,32)
            if (hh < 21)              m1 = fmaxf(m1, e); // rows [0,21)
            if (hh >= 11)             m2 = fmaxf(m2, e); // rows [11,32)
            if (hh < 16)              m3 = fmaxf(m3, e); // rows [0,16)
            if (hh >= 8 && hh < 24)   m4 = fmaxf(m4, e); // rows [8,24)
            if (hh >= 16)             m5 = fmaxf(m5, e); // rows [16,32)
        }
        rmax[tile][0][w] = m0; rmax[tile][1][w] = m1; rmax[tile][2][w] = m2;
        rmax[tile][3][w] = m3; rmax[tile][4][w] = m4; rmax[tile][5][w] = m5;
    }
    __syncthreads();

    // ---- 14 region reductions over column ranges (4 tiles * 14 = 56 threads) ----
    if (t < TPB * 14) {
        const int tl = t / 14;
        const int r  = t % 14;
        // region -> (row-range idx, col_lo, col_hi)
        const int rr_[14] = {0, 1, 1, 2, 2, 3, 3, 3, 4, 4, 4, 5, 5, 5};
        const int clo[14] = {0, 0, 11, 0, 11, 0, 8, 16, 0, 8, 16, 0, 8, 16};
        const int chi[14] = {32, 21, 32, 21, 32, 16, 24, 32, 16, 24, 32, 16, 24, 32};
        const float* src = rmax[tl][rr_[r]];
        float m = -INFINITY;
        for (int c = clo[r]; c < chi[r]; ++c) m = fmaxf(m, src[c]);
        vt[r * BC + blockIdx.x * TPB + tl] = m;
    }
}

__global__ __launch_bounds__(512) void rmac_norm_kernel(const float* __restrict__ vt,
                                                        float* __restrict__ out) {
    const int b = blockIdx.x;
    const int c = threadIdx.x;

    float v[14];
#pragma unroll
    for (int r = 0; r < 14; ++r) v[r] = vt[r * BC + b * C_ + c];

    __shared__ float partial[14][8];
    __shared__ float inv[14];
    const int wid  = c >> 6;
    const int lane = c & 63;

#pragma unroll
    for (int r = 0; r < 14; ++r) {
        float s = v[r] * v[r];
#pragma unroll
        for (int off = 32; off > 0; off >>= 1)
            s += __shfl_down(s, off, 64);
        if (lane == 0) partial[r][wid] = s;
    }
    __syncthreads();

    if (c < 14) {
        float s = 0.f;
#pragma unroll
        for (int wI = 0; wI < 8; ++wI) s += partial[c][wI];
        inv[c] = 1.0f / (sqrtf(s) + 1e-6f);
    }
    __syncthreads();

    float acc = 2.0f * v[0] * inv[0];   // r0 counted twice (global pool == l=1 region)
#pragma unroll
    for (int r = 1; r < 14; ++r) acc += v[r] * inv[r];
    out[b * C_ + c] = acc;
}

extern "C" void kernel_launch(void* const* d_in, const int* in_sizes, int n_in,
                              void* d_out, int out_size, void* d_ws, size_t ws_size,
                              hipStream_t stream) {
    const float* x  = (const float*)d_in[0];
    float* out      = (float*)d_out;
    float* vt       = (float*)d_ws;   // 14 * 32768 floats = 1.75 MB

    rmac_pool_kernel<<<BC / TPB, 256, 0, stream>>>(x, vt);   // 8192 blocks
    rmac_norm_kernel<<<B_, 512, 0, stream>>>(vt, out);       // 64 blocks
}